// Round 13
// baseline (320.430 us; speedup 1.0000x reference)
//
#include <hip/hip_runtime.h>

#define B_ 4096
#define T_ 256
#define I_ 16
#define H_ 32

typedef _Float16 f16x8 __attribute__((ext_vector_type(8)));
typedef float    f32x4 __attribute__((ext_vector_type(4)));

#define MSIG  (-1.442695041f)
#define MTANH (-2.885390082f)

__device__ __forceinline__ float sigm_(float a) {
    return __builtin_amdgcn_rcpf(1.0f + __builtin_amdgcn_exp2f(MSIG * a));
}
__device__ __forceinline__ float tanh_(float a) {
    return __fmaf_rn(2.0f, __builtin_amdgcn_rcpf(1.0f + __builtin_amdgcn_exp2f(MTANH * a)), -1.0f);
}

// Single-wave lane-local MFMA LSTM. 1 wave = 16 batch elems, all 8 gate-tiles.
// Row permutation: parity-p tile, in-tile row m -> hidden col j = (m>>2)*8+p*4+(m&3).
// A-frag lane map (HW-verified r11): lane holds A[m=l&15][k=(l>>4)*8..+8];
// C/D (m89): col=l&15, row=(l>>4)*4+reg. So lane (lg,r) gets j = lg*8+p*4+r
// == exactly its OWN next-step B-fragment k-slice (k=j identity).
// => h never leaves the lane: no LDS, no barrier, no shuffle in the T-loop.
// x-part zero-padded to K=32 via zero A-fragments on lanes lg>=2 (r11-verified).
// Bias enters as MFMA C-in. Grid 256 blocks x 64 thr (parallelism cap = B/16).
__global__ __launch_bounds__(64, 1)
void lstm_wave(const float* __restrict__ x,
               const float* __restrict__ Wih,
               const float* __restrict__ Whh,
               const float* __restrict__ bih,
               const float* __restrict__ bhh,
               const float* __restrict__ Wfc,
               const float* __restrict__ bfc,
               float* __restrict__ out)
{
    const int l  = threadIdx.x & 63;
    const int lr = l & 15;   // elem (B n / C col); A row m
    const int lg = l >> 4;   // k-group; C row-group
    const int b0 = blockIdx.x * 16;

    // ---- static A-fragments (permuted rows) + bias C-fragments ----
    f16x8 whhA[4][2];
    f16x8 wihA[4][2];
    f32x4 biasC[4][2];
    const int jA0 = ((lr >> 2) * 8) + (lr & 3);   // j for parity 0; +4 for parity 1
#pragma unroll
    for (int q = 0; q < 4; ++q) {
#pragma unroll
        for (int p = 0; p < 2; ++p) {
            const int row = q * 32 + jA0 + p * 4;
            const float* ph = Whh + row * H_ + lg * 8;
            f16x8 w;
#pragma unroll
            for (int k = 0; k < 8; ++k) w[k] = (_Float16)ph[k];
            whhA[q][p] = w;
            const float* pi = Wih + row * I_ + (lg & 1) * 8;
            f16x8 wi;
#pragma unroll
            for (int k = 0; k < 8; ++k)
                wi[k] = (lg < 2) ? (_Float16)pi[k] : (_Float16)0.0f;
            wihA[q][p] = wi;
            f32x4 bc;
#pragma unroll
            for (int r = 0; r < 4; ++r) {
                const int jC = lg * 8 + p * 4 + r;   // this lane's C rows -> hidden j
                bc[r] = bih[q * 32 + jC] + bhh[q * 32 + jC];
            }
            biasC[q][p] = bc;
        }
    }

    // ---- x stream: lane holds x[b0+lr][t][(lg&1)*8 .. +8] as f16x8 ----
    const float* xbase = x + (size_t)(b0 + lr) * (T_ * I_) + (lg & 1) * 8;
    f16x8 xf[8];
#pragma unroll
    for (int t = 0; t < 8; ++t) {
        const float4 u0 = *reinterpret_cast<const float4*>(xbase + t * I_);
        const float4 u1 = *reinterpret_cast<const float4*>(xbase + t * I_ + 4);
        f16x8 w;
        w[0] = (_Float16)u0.x; w[1] = (_Float16)u0.y;
        w[2] = (_Float16)u0.z; w[3] = (_Float16)u0.w;
        w[4] = (_Float16)u1.x; w[5] = (_Float16)u1.y;
        w[6] = (_Float16)u1.z; w[7] = (_Float16)u1.w;
        xf[t] = w;
    }

    f16x8 hB;
#pragma unroll
    for (int k = 0; k < 8; ++k) hB[k] = (_Float16)0.0f;
    f32x4 cc0 = {0.f, 0.f, 0.f, 0.f};
    f32x4 cc1 = {0.f, 0.f, 0.f, 0.f};
    f32x4 hE = {0.f, 0.f, 0.f, 0.f};
    f32x4 hO = {0.f, 0.f, 0.f, 0.f};

    for (int tb = 0; tb < 32; ++tb) {          // 32 chunks x 8 steps
#pragma unroll
        for (int tt = 0; tt < 8; ++tt) {
            const f16x8 xB = xf[tt];
            if (tb < 31) {
                const float* nx = xbase + ((tb + 1) * 8 + tt) * I_;
                const float4 u0 = *reinterpret_cast<const float4*>(nx);
                const float4 u1 = *reinterpret_cast<const float4*>(nx + 4);
                f16x8 w;
                w[0] = (_Float16)u0.x; w[1] = (_Float16)u0.y;
                w[2] = (_Float16)u0.z; w[3] = (_Float16)u0.w;
                w[4] = (_Float16)u1.x; w[5] = (_Float16)u1.y;
                w[6] = (_Float16)u1.z; w[7] = (_Float16)u1.w;
                xf[tt] = w;
            }

            // 8 tiles: x-part (bias C-in) then h-part accumulate
            f32x4 aQ[4][2];
#pragma unroll
            for (int q = 0; q < 4; ++q)
#pragma unroll
                for (int p = 0; p < 2; ++p)
                    aQ[q][p] = __builtin_amdgcn_mfma_f32_16x16x32_f16(wihA[q][p], xB, biasC[q][p], 0, 0, 0);
#pragma unroll
            for (int q = 0; q < 4; ++q)
#pragma unroll
                for (int p = 0; p < 2; ++p)
                    aQ[q][p] = __builtin_amdgcn_mfma_f32_16x16x32_f16(whhA[q][p], hB, aQ[q][p], 0, 0, 0);

            // lane-local activations + c/h update (j = lg*8 + p*4 + r)
#pragma unroll
            for (int r = 0; r < 4; ++r) {
                const float i0 = sigm_(aQ[0][0][r]);
                const float f0 = sigm_(aQ[1][0][r]);
                const float g0 = tanh_(aQ[2][0][r]);
                const float o0 = sigm_(aQ[3][0][r]);
                cc0[r] = __fmaf_rn(f0, cc0[r], i0 * g0);
                hE[r]  = o0 * tanh_(cc0[r]);
                const float i1 = sigm_(aQ[0][1][r]);
                const float f1 = sigm_(aQ[1][1][r]);
                const float g1 = tanh_(aQ[2][1][r]);
                const float o1 = sigm_(aQ[3][1][r]);
                cc1[r] = __fmaf_rn(f1, cc1[r], i1 * g1);
                hO[r]  = o1 * tanh_(cc1[r]);
            }

            // repack next-step B-fragment (lane-local, k = j identity)
            f16x8 nh;
#pragma unroll
            for (int r = 0; r < 4; ++r) {
                nh[r]     = (_Float16)hE[r];
                nh[4 + r] = (_Float16)hO[r];
            }
            hB = nh;
        }
    }

    // ---- FC epilogue: lane owns h_last[e=lr][j = lg*8 .. +8] ----
    const float* pw = Wfc + lg * 8;
    float pacc = 0.f;
#pragma unroll
    for (int r = 0; r < 4; ++r)
        pacc += hE[r] * pw[r] + hO[r] * pw[4 + r];
    pacc += __shfl_xor(pacc, 16, 64);
    pacc += __shfl_xor(pacc, 32, 64);
    if (lg == 0) out[b0 + lr] = pacc + bfc[0];
}

extern "C" void kernel_launch(void* const* d_in, const int* in_sizes, int n_in,
                              void* d_out, int out_size, void* d_ws, size_t ws_size,
                              hipStream_t stream) {
    const float* x   = (const float*)d_in[0];
    const float* Wih = (const float*)d_in[1];
    const float* Whh = (const float*)d_in[2];
    const float* bih = (const float*)d_in[3];
    const float* bhh = (const float*)d_in[4];
    const float* Wfc = (const float*)d_in[5];
    const float* bfc = (const float*)d_in[6];
    float* out = (float*)d_out;

    dim3 grid(B_ / 16);
    dim3 block(64);
    hipLaunchKernelGGL(lstm_wave, grid, block, 0, stream,
                       x, Wih, Whh, bih, bhh, Wfc, bfc, out);
}